// Round 7
// baseline (71.032 us; speedup 1.0000x reference)
//
#include <hip/hip_runtime.h>

#if __has_builtin(__builtin_amdgcn_exp2f)
__device__ __forceinline__ float fast_exp2(float x) { return __builtin_amdgcn_exp2f(x); }
#else
__device__ __forceinline__ float fast_exp2(float x) { return exp2f(x); }
#endif

typedef float f32x2 __attribute__((ext_vector_type(2)));

// VOP3P packed-fp32 (gfx90a+, present on gfx950). All sources must be
// 64-bit VGPR pairs — scalar src with op_sel does NOT assemble (R6 lesson).
__device__ __forceinline__ f32x2 pk_add(f32x2 a, f32x2 b) {
    f32x2 d;
    asm("v_pk_add_f32 %0, %1, %2" : "=v"(d) : "v"(a), "v"(b));
    return d;
}
__device__ __forceinline__ f32x2 pk_mul(f32x2 a, f32x2 b) {
    f32x2 d;
    asm("v_pk_mul_f32 %0, %1, %2" : "=v"(d) : "v"(a), "v"(b));
    return d;
}
__device__ __forceinline__ f32x2 pk_fma(f32x2 a, f32x2 b, f32x2 c) {
    f32x2 d;
    asm("v_pk_fma_f32 %0, %1, %2, %3" : "=v"(d) : "v"(a), "v"(b), "v"(c));
    return d;
}

constexpr int C_ = 256;   // centers
constexpr int M_ = 5;     // ensemble size
constexpr float LOG2E = 1.4426950408889634f;

// out[m,n,d] = sum_c exp(-||x_n - c||^2) * sigma^2 * W[m,c,d],  sigma^2 = 1/16
// exp(-d2)/16 = exp2(-d2*log2e - 4)
//
// R2 structure (measured best: 70.6us; A/A noise +-0.1us): block = 64 n x
// 4 c-chunks, wave-uniform c -> LDS broadcasts, LDS tree combine. Packed
// fp32 math cuts the inner loop ~15 -> ~11 wave-instrs per (n,c). Table
// stores NEGATED centers so the distance is a pk_add.
__global__ __launch_bounds__(256) void ensemble_rbf_kernel(
    const float* __restrict__ x,        // [N,2]
    const float* __restrict__ centers,  // [256,2]
    const float* __restrict__ weights,  // [5,256,2]
    float* __restrict__ out,            // [5,N,2]
    int N)
{
    // packed table: per center c, 12 floats {-cx, -cy, w0..w9}, 48B row.
    // reused after the main loop as the reduction scratch [4][64][12]
    __shared__ float s_tab[C_ * 12];

    const int tid   = threadIdx.x;
    const int nl    = tid & 63;     // local n (lane)
    const int chunk = tid >> 6;     // wave id = c-chunk

    // ---- stage packed table: thread t fills row t ----
    {
        float2 cv = ((const float2*)centers)[tid];
        float* row = &s_tab[tid * 12];
        row[0] = -cv.x;
        row[1] = -cv.y;
        const float2* w2 = (const float2*)weights;   // [5][256] float2
        #pragma unroll
        for (int m = 0; m < M_; m++) {
            float2 wv = w2[m * C_ + tid];            // coalesced
            row[2 + 2 * m]     = wv.x;
            row[2 + 2 * m + 1] = wv.y;
        }
    }
    __syncthreads();

    const int n = blockIdx.x * 64 + nl;
    float2 xvl = (n < N) ? ((const float2*)x)[n] : make_float2(0.f, 0.f);
    f32x2 xv = { xvl.x, xvl.y };

    f32x2 acc[M_];
    #pragma unroll
    for (int m = 0; m < M_; m++) acc[m] = f32x2{0.f, 0.f};

    const float4* tab4 = (const float4*)s_tab;
    const int cbase = chunk * 64;

    #pragma unroll 8
    for (int cc = 0; cc < 64; cc++) {
        int c = cbase + cc;                 // wave-uniform -> LDS broadcast
        float4 t0 = tab4[c * 3 + 0];        // {-cx, -cy, w0, w1}
        float4 t1 = tab4[c * 3 + 1];        // {w2, w3, w4, w5}
        float4 t2 = tab4[c * 3 + 2];        // {w6, w7, w8, w9}

        f32x2 dxy = pk_add(xv, f32x2{t0.x, t0.y});   // x - c
        f32x2 sq  = pk_mul(dxy, dxy);
        float d2  = sq.x + sq.y;
        float r   = fast_exp2(fmaf(d2, -LOG2E, -4.0f));   // exp(-d2)/16
        f32x2 rr  = { r, r };

        acc[0] = pk_fma(rr, f32x2{t0.z, t0.w}, acc[0]);
        acc[1] = pk_fma(rr, f32x2{t1.x, t1.y}, acc[1]);
        acc[2] = pk_fma(rr, f32x2{t1.z, t1.w}, acc[2]);
        acc[3] = pk_fma(rr, f32x2{t2.x, t2.y}, acc[3]);
        acc[4] = pk_fma(rr, f32x2{t2.z, t2.w}, acc[4]);
    }

    // ---- combine the 4 chunk-partials per n via LDS ----
    __syncthreads();   // everyone done reading the table
    {
        float4* slot = (float4*)&s_tab[(chunk * 64 + nl) * 12];
        slot[0] = make_float4(acc[0].x, acc[0].y, acc[1].x, acc[1].y);
        slot[1] = make_float4(acc[2].x, acc[2].y, acc[3].x, acc[3].y);
        slot[2] = make_float4(acc[4].x, acc[4].y, 0.f, 0.f);
    }
    __syncthreads();

    if (tid < 64 && n < N) {
        float4 s0 = make_float4(0.f, 0.f, 0.f, 0.f);
        float4 s1 = s0, s2 = s0;
        #pragma unroll
        for (int k = 0; k < 4; k++) {
            const float4* slot = (const float4*)&s_tab[(k * 64 + nl) * 12];
            float4 r0 = slot[0], r1 = slot[1], r2 = slot[2];
            s0.x += r0.x; s0.y += r0.y; s0.z += r0.z; s0.w += r0.w;
            s1.x += r1.x; s1.y += r1.y; s1.z += r1.z; s1.w += r1.w;
            s2.x += r2.x; s2.y += r2.y;
        }
        float2* out2 = (float2*)out;
        out2[(size_t)0 * N + n] = make_float2(s0.x, s0.y);
        out2[(size_t)1 * N + n] = make_float2(s0.z, s0.w);
        out2[(size_t)2 * N + n] = make_float2(s1.x, s1.y);
        out2[(size_t)3 * N + n] = make_float2(s1.z, s1.w);
        out2[(size_t)4 * N + n] = make_float2(s2.x, s2.y);
    }
}

extern "C" void kernel_launch(void* const* d_in, const int* in_sizes, int n_in,
                              void* d_out, int out_size, void* d_ws, size_t ws_size,
                              hipStream_t stream) {
    const float* x       = (const float*)d_in[0];  // [N,2]
    const float* centers = (const float*)d_in[1];  // [256,2]
    const float* weights = (const float*)d_in[2];  // [5,256,2]
    float* out = (float*)d_out;                    // [5,N,2]

    int N = in_sizes[0] / 2;
    int grid = (N + 63) / 64;   // 64 n per block
    ensemble_rbf_kernel<<<grid, 256, 0, stream>>>(x, centers, weights, out, N);
}